// Round 1
// baseline (339.369 us; speedup 1.0000x reference)
//
#include <hip/hip_runtime.h>

// ---------------------------------------------------------------------------
// MultiHeadDotProductAttention: rotary + sliding-window (|i-j|<=256) MHA
// B=4 T=2048 E=1024 H=16x64=1024.  bf16 MFMA (16x16x32) for all matmuls.
//
// Pipeline:
//   1) cvt:     Xq,Xkv f32 -> bf16            (ws)
//   2) wtrans:  Wq,Wk,Wv,Wo f32 -> bf16 W^T   (ws)  [N][K] layout
//   3) proj_gemm (grid.z=0,1,2): Q/K/V = X @ W, rotary fused for Q,K -> bf16
//   4) attn:    flash-style banded attention -> bf16 A buffer
//   5) out_gemm: out = A @ Wo^T -> f32 d_out
//
// Verified layout facts used (learn_hip m89/m91/m120):
//   mfma_f32_16x16x32_bf16: A[m=lane&15][k=(lane>>4)*8+j], B[k=(lane>>4)*8+j][n=lane&15]
//   C/D: col=lane&15, row=(lane>>4)*4+reg
// ---------------------------------------------------------------------------

typedef __attribute__((ext_vector_type(8))) short s8v;    // 8 x bf16 (4 VGPR)
typedef __attribute__((ext_vector_type(4))) float f4v;    // MFMA acc
typedef __attribute__((ext_vector_type(8))) unsigned short u8v;

#define MFMA_BF16 __builtin_amdgcn_mfma_f32_16x16x32_bf16

__device__ __forceinline__ unsigned short f2bf(float f) {
  union { float f; unsigned int u; } v; v.f = f;
  unsigned int r = (v.u + 0x7fffu + ((v.u >> 16) & 1u)) >> 16;  // RNE
  return (unsigned short)r;
}

// ---------------- 1) f32 -> bf16 cast (8.4M elems, 4/thread) ----------------
__global__ __launch_bounds__(256) void cvt_kernel(const float* __restrict__ src,
                                                  unsigned short* __restrict__ dst) {
  int i = (blockIdx.x * 256 + threadIdx.x) * 4;
  float4 v = *(const float4*)(src + i);
  ushort4 o;
  o.x = f2bf(v.x); o.y = f2bf(v.y); o.z = f2bf(v.z); o.w = f2bf(v.w);
  *(ushort4*)(dst + i) = o;
}

// ---------------- 2) weight transpose + cast: Wt[n][k] = bf16(W[k][n]) ------
__global__ __launch_bounds__(256) void wtrans_kernel(
    const float* __restrict__ W0, const float* __restrict__ W1,
    const float* __restrict__ W2, const float* __restrict__ W3,
    unsigned short* __restrict__ D0, unsigned short* __restrict__ D1,
    unsigned short* __restrict__ D2, unsigned short* __restrict__ D3) {
  const float* W = blockIdx.z == 0 ? W0 : blockIdx.z == 1 ? W1 : blockIdx.z == 2 ? W2 : W3;
  unsigned short* D = blockIdx.z == 0 ? D0 : blockIdx.z == 1 ? D1 : blockIdx.z == 2 ? D2 : D3;
  __shared__ float tile[32][33];
  int n0 = blockIdx.x * 32, k0 = blockIdx.y * 32;
  int tx = threadIdx.x & 31, ty = threadIdx.x >> 5;  // 32 x 8
#pragma unroll
  for (int r = 0; r < 32; r += 8)
    tile[ty + r][tx] = W[(size_t)(k0 + ty + r) * 1024 + n0 + tx];
  __syncthreads();
#pragma unroll
  for (int r = 0; r < 32; r += 8)
    D[(size_t)(n0 + ty + r) * 1024 + k0 + tx] = f2bf(tile[tx][ty + r]);
}

// ---------------- 3) projection GEMM (+rotary epilogue for z<2) -------------
// C[8192][1024] = A[8192][1024] @ Bt[1024][1024]^T ; 64x64 block tile, BK=64.
// 4 waves in 2x2; each wave 32x32 (2x2 MFMA tiles).
__global__ __launch_bounds__(256) void proj_gemm(
    const unsigned short* __restrict__ XqBf, const unsigned short* __restrict__ XkvBf,
    const unsigned short* __restrict__ Wtq, const unsigned short* __restrict__ Wtk,
    const unsigned short* __restrict__ Wtv,
    unsigned short* __restrict__ Qb, unsigned short* __restrict__ Kb,
    unsigned short* __restrict__ Vb) {
  const int K = 1024;
  int z = blockIdx.z;
  const unsigned short* A  = (z == 0) ? XqBf : XkvBf;
  const unsigned short* Bt = (z == 0) ? Wtq : (z == 1) ? Wtk : Wtv;
  unsigned short* Cb       = (z == 0) ? Qb  : (z == 1) ? Kb  : Vb;

  __shared__ __align__(16) unsigned short sA[64][72];  // [m][k], +8 pad
  __shared__ __align__(16) unsigned short sB[64][72];  // [n][k], +8 pad

  int tid = threadIdx.x;
  int lane = tid & 63, wave = tid >> 6;
  int quad = lane >> 4, l16 = lane & 15;
  int wm = wave & 1, wn = wave >> 1;
  int m_blk = blockIdx.y * 64, n_blk = blockIdx.x * 64;

  f4v acc[2][2] = {};
  int srow = tid >> 2;            // 0..63
  int sseg = (tid & 3) * 16;      // 0,16,32,48 (elements)
  const unsigned short* gA = A + (size_t)(m_blk + srow) * K + sseg;
  const unsigned short* gB = Bt + (size_t)(n_blk + srow) * K + sseg;

  for (int k0 = 0; k0 < K; k0 += 64) {
    uint4 a0 = *(const uint4*)(gA + k0);
    uint4 a1 = *(const uint4*)(gA + k0 + 8);
    uint4 b0 = *(const uint4*)(gB + k0);
    uint4 b1 = *(const uint4*)(gB + k0 + 8);
    __syncthreads();
    *(uint4*)&sA[srow][sseg] = a0;
    *(uint4*)&sA[srow][sseg + 8] = a1;
    *(uint4*)&sB[srow][sseg] = b0;
    *(uint4*)&sB[srow][sseg + 8] = b1;
    __syncthreads();
#pragma unroll
    for (int ks = 0; ks < 64; ks += 32) {
      s8v af0 = *(const s8v*)&sA[wm * 32 + l16][ks + quad * 8];
      s8v af1 = *(const s8v*)&sA[wm * 32 + 16 + l16][ks + quad * 8];
      s8v bf0 = *(const s8v*)&sB[wn * 32 + l16][ks + quad * 8];
      s8v bf1 = *(const s8v*)&sB[wn * 32 + 16 + l16][ks + quad * 8];
      acc[0][0] = MFMA_BF16(af0, bf0, acc[0][0], 0, 0, 0);
      acc[0][1] = MFMA_BF16(af0, bf1, acc[0][1], 0, 0, 0);
      acc[1][0] = MFMA_BF16(af1, bf0, acc[1][0], 0, 0, 0);
      acc[1][1] = MFMA_BF16(af1, bf1, acc[1][1], 0, 0, 0);
    }
  }

  // epilogue: C/D layout col=lane&15, row=quad*4+r.  Rotary for z<2.
#pragma unroll
  for (int mt = 0; mt < 2; ++mt)
#pragma unroll
    for (int nt = 0; nt < 2; ++nt)
#pragma unroll
      for (int r = 0; r < 4; ++r) {
        int row = m_blk + wm * 32 + mt * 16 + quad * 4 + r;
        int col = n_blk + wn * 32 + nt * 16 + l16;
        float v = acc[mt][nt][r];
        float other = __shfl_xor(v, 1);  // pair partner: same row, col^1
        if (z < 2) {
          int dh = col & 63;          // dim within head
          int tpos = row & 2047;      // t within sequence (T=2048)
          float fi = (float)(dh >> 1) * (1.0f / 32.0f);
          float invf = __expf(-9.210340371976184f * fi);  // 10000^{-i/32}
          float ang = (float)tpos * invf;
          float s = sinf(ang), c = cosf(ang);
          v = (dh & 1) ? (v * c + other * s) : (v * c - other * s);
        }
        Cb[(size_t)row * 1024 + col] = f2bf(v);
      }
}

// ---------------- 4) banded flash attention ---------------------------------
// grid (T/64=32, H=16, B=4), 4 waves; wave w owns q rows t0+16w..+15.
__global__ __launch_bounds__(256) void attn_kernel(
    const unsigned short* __restrict__ Qb, const unsigned short* __restrict__ Kb,
    const unsigned short* __restrict__ Vb, unsigned short* __restrict__ Ab) {
  const int T = 2048;
  int t0 = blockIdx.x * 64;
  int h = blockIdx.y;
  int b = blockIdx.z;
  int tid = threadIdx.x, lane = tid & 63, wave = tid >> 6;
  int quad = lane >> 4, l16 = lane & 15;

  __shared__ __align__(16) unsigned short sQ[64][72];      // [qrow][d]
  __shared__ __align__(16) unsigned short sK[64][72];      // [key][d]
  __shared__ __align__(16) unsigned short sV[64][72];      // [d][key] (transposed)
  __shared__ __align__(16) unsigned short sP[4][16][72];   // per-wave P round-trip

  size_t base = ((size_t)b * T) * 1024 + (size_t)h * 64;
  int srow = tid >> 2, sseg = (tid & 3) * 16;

  {  // stage Q once
    const unsigned short* g = Qb + base + (size_t)(t0 + srow) * 1024 + sseg;
    *(uint4*)&sQ[srow][sseg] = *(const uint4*)g;
    *(uint4*)&sQ[srow][sseg + 8] = *(const uint4*)(g + 8);
  }
  __syncthreads();
  s8v aq0 = *(const s8v*)&sQ[wave * 16 + l16][quad * 8];
  s8v aq1 = *(const s8v*)&sQ[wave * 16 + l16][32 + quad * 8];

  f4v oacc[4] = {};
  float mrow[4], lrow[4];
#pragma unroll
  for (int r = 0; r < 4; ++r) { mrow[r] = -1e30f; lrow[r] = 0.0f; }

  int kv_lo = max(0, t0 - 256);
  int kv_hi = min(T, t0 + 64 + 256);  // both multiples of 64

  for (int kv0 = kv_lo; kv0 < kv_hi; kv0 += 64) {
    __syncthreads();  // protect previous tile's sK/sV reads
    {  // stage K row-major
      const unsigned short* g = Kb + base + (size_t)(kv0 + srow) * 1024 + sseg;
      *(uint4*)&sK[srow][sseg] = *(const uint4*)g;
      *(uint4*)&sK[srow][sseg + 8] = *(const uint4*)(g + 8);
    }
    {  // stage V transposed: sV[d][key]
      int key = tid >> 2;
      int d0 = (tid & 3) * 16;
      const unsigned short* g = Vb + base + (size_t)(kv0 + key) * 1024 + d0;
      u8v v0 = *(const u8v*)g;
      u8v v1 = *(const u8v*)(g + 8);
#pragma unroll
      for (int j = 0; j < 8; ++j) sV[d0 + j][key] = v0[j];
#pragma unroll
      for (int j = 0; j < 8; ++j) sV[d0 + 8 + j][key] = v1[j];
    }
    __syncthreads();

    // S = Q K^T  (16 rows x 64 keys per wave)
    f4v sacc[4];
#pragma unroll
    for (int nt = 0; nt < 4; ++nt) {
      s8v b0 = *(const s8v*)&sK[nt * 16 + l16][quad * 8];
      s8v b1 = *(const s8v*)&sK[nt * 16 + l16][32 + quad * 8];
      f4v zz = {};
      zz = MFMA_BF16(aq0, b0, zz, 0, 0, 0);
      sacc[nt] = MFMA_BF16(aq1, b1, zz, 0, 0, 0);
    }

    // scale + band mask + online softmax (row stats live per quad)
    int qg = t0 + wave * 16 + quad * 4;  // +r
    float p[4][4];  // [nt][r]
    float mx[4];
#pragma unroll
    for (int r = 0; r < 4; ++r) mx[r] = -1e30f;
#pragma unroll
    for (int nt = 0; nt < 4; ++nt) {
      int kg = kv0 + nt * 16 + l16;
#pragma unroll
      for (int r = 0; r < 4; ++r) {
        int d = qg + r - kg;
        float s = sacc[nt][r] * 0.125f;
        s = (d <= 256 && d >= -256) ? s : -1e30f;
        p[nt][r] = s;
        mx[r] = fmaxf(mx[r], s);
      }
    }
#pragma unroll
    for (int off = 1; off < 16; off <<= 1)
#pragma unroll
      for (int r = 0; r < 4; ++r) mx[r] = fmaxf(mx[r], __shfl_xor(mx[r], off));

    float alpha[4], rsum[4];
#pragma unroll
    for (int r = 0; r < 4; ++r) {
      float mn = fmaxf(mrow[r], mx[r]);
      alpha[r] = __expf(mrow[r] - mn);  // 0 on first tile (mrow=-1e30)
      mrow[r] = mn;
      rsum[r] = 0.0f;
    }
#pragma unroll
    for (int nt = 0; nt < 4; ++nt)
#pragma unroll
      for (int r = 0; r < 4; ++r) {
        float e = __expf(p[nt][r] - mrow[r]);  // masked: exp(-1e30)->0
        p[nt][r] = e;
        rsum[r] += e;
      }
#pragma unroll
    for (int off = 1; off < 16; off <<= 1)
#pragma unroll
      for (int r = 0; r < 4; ++r) rsum[r] += __shfl_xor(rsum[r], off);
#pragma unroll
    for (int r = 0; r < 4; ++r) {
      lrow[r] = lrow[r] * alpha[r] + rsum[r];
#pragma unroll
      for (int dt = 0; dt < 4; ++dt) oacc[dt][r] *= alpha[r];
    }

    // P: C-layout -> LDS -> A-layout (per-wave, no barrier needed)
#pragma unroll
    for (int nt = 0; nt < 4; ++nt)
#pragma unroll
      for (int r = 0; r < 4; ++r)
        sP[wave][quad * 4 + r][nt * 16 + l16] = f2bf(p[nt][r]);
    s8v pa0 = *(const s8v*)&sP[wave][l16][quad * 8];
    s8v pa1 = *(const s8v*)&sP[wave][l16][32 + quad * 8];

    // O += P V   (V as B operand from transposed sV)
#pragma unroll
    for (int dt = 0; dt < 4; ++dt) {
      s8v bv0 = *(const s8v*)&sV[dt * 16 + l16][quad * 8];
      s8v bv1 = *(const s8v*)&sV[dt * 16 + l16][32 + quad * 8];
      oacc[dt] = MFMA_BF16(pa0, bv0, oacc[dt], 0, 0, 0);
      oacc[dt] = MFMA_BF16(pa1, bv1, oacc[dt], 0, 0, 0);
    }
  }

  // normalize + store bf16
  float inv_l[4];
#pragma unroll
  for (int r = 0; r < 4; ++r) inv_l[r] = 1.0f / lrow[r];
#pragma unroll
  for (int dt = 0; dt < 4; ++dt)
#pragma unroll
    for (int r = 0; r < 4; ++r) {
      int row = t0 + wave * 16 + quad * 4 + r;
      int col = dt * 16 + l16;
      Ab[base + (size_t)row * 1024 + col] = f2bf(oacc[dt][r] * inv_l[r]);
    }
}

// ---------------- 5) output GEMM: f32 out ------------------------------------
__global__ __launch_bounds__(256) void out_gemm(
    const unsigned short* __restrict__ A, const unsigned short* __restrict__ Bt,
    float* __restrict__ C) {
  const int K = 1024;
  __shared__ __align__(16) unsigned short sA[64][72];
  __shared__ __align__(16) unsigned short sB[64][72];

  int tid = threadIdx.x;
  int lane = tid & 63, wave = tid >> 6;
  int quad = lane >> 4, l16 = lane & 15;
  int wm = wave & 1, wn = wave >> 1;
  int m_blk = blockIdx.y * 64, n_blk = blockIdx.x * 64;

  f4v acc[2][2] = {};
  int srow = tid >> 2;
  int sseg = (tid & 3) * 16;
  const unsigned short* gA = A + (size_t)(m_blk + srow) * K + sseg;
  const unsigned short* gB = Bt + (size_t)(n_blk + srow) * K + sseg;

  for (int k0 = 0; k0 < K; k0 += 64) {
    uint4 a0 = *(const uint4*)(gA + k0);
    uint4 a1 = *(const uint4*)(gA + k0 + 8);
    uint4 b0 = *(const uint4*)(gB + k0);
    uint4 b1 = *(const uint4*)(gB + k0 + 8);
    __syncthreads();
    *(uint4*)&sA[srow][sseg] = a0;
    *(uint4*)&sA[srow][sseg + 8] = a1;
    *(uint4*)&sB[srow][sseg] = b0;
    *(uint4*)&sB[srow][sseg + 8] = b1;
    __syncthreads();
#pragma unroll
    for (int ks = 0; ks < 64; ks += 32) {
      s8v af0 = *(const s8v*)&sA[wm * 32 + l16][ks + quad * 8];
      s8v af1 = *(const s8v*)&sA[wm * 32 + 16 + l16][ks + quad * 8];
      s8v bf0 = *(const s8v*)&sB[wn * 32 + l16][ks + quad * 8];
      s8v bf1 = *(const s8v*)&sB[wn * 32 + 16 + l16][ks + quad * 8];
      acc[0][0] = MFMA_BF16(af0, bf0, acc[0][0], 0, 0, 0);
      acc[0][1] = MFMA_BF16(af0, bf1, acc[0][1], 0, 0, 0);
      acc[1][0] = MFMA_BF16(af1, bf0, acc[1][0], 0, 0, 0);
      acc[1][1] = MFMA_BF16(af1, bf1, acc[1][1], 0, 0, 0);
    }
  }

#pragma unroll
  for (int mt = 0; mt < 2; ++mt)
#pragma unroll
    for (int nt = 0; nt < 2; ++nt)
#pragma unroll
      for (int r = 0; r < 4; ++r) {
        int row = m_blk + wm * 32 + mt * 16 + quad * 4 + r;
        int col = n_blk + wn * 32 + nt * 16 + l16;
        C[(size_t)row * 1024 + col] = acc[mt][nt][r];
      }
}

// ---------------- launch -----------------------------------------------------
extern "C" void kernel_launch(void* const* d_in, const int* in_sizes, int n_in,
                              void* d_out, int out_size, void* d_ws, size_t ws_size,
                              hipStream_t stream) {
  const float* Xq  = (const float*)d_in[0];
  const float* Xkv = (const float*)d_in[1];
  const float* Wq  = (const float*)d_in[2];
  const float* Wk  = (const float*)d_in[3];
  const float* Wv  = (const float*)d_in[4];
  const float* Wo  = (const float*)d_in[5];
  float* out = (float*)d_out;

  char* ws = (char*)d_ws;
  const size_t MB = 1ull << 20;
  unsigned short* XqBf  = (unsigned short*)(ws + 0 * MB);   // 16 MiB
  unsigned short* XkvBf = (unsigned short*)(ws + 16 * MB);  // 16 MiB
  unsigned short* Wtq   = (unsigned short*)(ws + 32 * MB);  // 2 MiB each
  unsigned short* Wtk   = (unsigned short*)(ws + 34 * MB);
  unsigned short* Wtv   = (unsigned short*)(ws + 36 * MB);
  unsigned short* Wto   = (unsigned short*)(ws + 38 * MB);
  unsigned short* Qb    = (unsigned short*)(ws + 40 * MB);  // 16 MiB
  unsigned short* Kb    = (unsigned short*)(ws + 56 * MB);  // 16 MiB
  unsigned short* Vb    = (unsigned short*)(ws + 72 * MB);  // 16 MiB
  unsigned short* Ab    = XqBf;  // reuse: XqBf dead after proj_gemm

  cvt_kernel<<<8192, 256, 0, stream>>>(Xq, XqBf);
  cvt_kernel<<<8192, 256, 0, stream>>>(Xkv, XkvBf);
  wtrans_kernel<<<dim3(32, 32, 4), 256, 0, stream>>>(Wq, Wk, Wv, Wo, Wtq, Wtk, Wtv, Wto);
  proj_gemm<<<dim3(16, 128, 3), 256, 0, stream>>>(XqBf, XkvBf, Wtq, Wtk, Wtv, Qb, Kb, Vb);
  attn_kernel<<<dim3(32, 16, 4), 256, 0, stream>>>(Qb, Kb, Vb, Ab);
  out_gemm<<<dim3(16, 128), 256, 0, stream>>>(Ab, Wto, out);
}

// Round 2
// 321.355 us; speedup vs baseline: 1.0561x; 1.0561x over previous
//
#include <hip/hip_runtime.h>

// ---------------------------------------------------------------------------
// MultiHeadDotProductAttention: rotary + sliding-window (|i-j|<=256) MHA
// B=4 T=2048 E=1024 H=16x64=1024.  bf16 MFMA (16x16x32) for all matmuls.
//
// R2: m97-style GEMMs (128x128 tile, BK=64, global_load_lds width=16,
//     4 waves x 4x4 acc) for proj and out; V written transposed in proj
//     epilogue so attn stages sV with vector copies (no scalar transpose).
//
// Verified layout facts (learn_hip m89/m91/m120):
//   mfma_f32_16x16x32_bf16: A[m=lane&15][k=(lane>>4)*8+j], B[k=...][n=lane&15]
//   C/D: col=lane&15, row=(lane>>4)*4+reg
// global_load_lds: LDS dest is wave-uniform base + lane*16 (m104/m108).
// ---------------------------------------------------------------------------

typedef __attribute__((ext_vector_type(8))) short s8v;    // 8 x bf16
typedef __attribute__((ext_vector_type(4))) float f4v;    // MFMA acc

#define MFMA_BF16 __builtin_amdgcn_mfma_f32_16x16x32_bf16

#define ASYNC_CP16(g, l)                                             \
  __builtin_amdgcn_global_load_lds(                                  \
      (const __attribute__((address_space(1))) void*)(g),            \
      (__attribute__((address_space(3))) void*)(l), 16, 0, 0)

__device__ __forceinline__ unsigned short f2bf(float f) {
  union { float f; unsigned int u; } v; v.f = f;
  unsigned int r = (v.u + 0x7fffu + ((v.u >> 16) & 1u)) >> 16;  // RNE
  return (unsigned short)r;
}

// ---------------- 1) f32 -> bf16 cast ----------------------------------------
__global__ __launch_bounds__(256) void cvt_kernel(const float* __restrict__ src,
                                                  unsigned short* __restrict__ dst) {
  int i = (blockIdx.x * 256 + threadIdx.x) * 4;
  float4 v = *(const float4*)(src + i);
  ushort4 o;
  o.x = f2bf(v.x); o.y = f2bf(v.y); o.z = f2bf(v.z); o.w = f2bf(v.w);
  *(ushort4*)(dst + i) = o;
}

// ---------------- 2) weight transpose + cast: Wt[n][k] = bf16(W[k][n]) -------
__global__ __launch_bounds__(256) void wtrans_kernel(
    const float* __restrict__ W0, const float* __restrict__ W1,
    const float* __restrict__ W2, const float* __restrict__ W3,
    unsigned short* __restrict__ D0, unsigned short* __restrict__ D1,
    unsigned short* __restrict__ D2, unsigned short* __restrict__ D3) {
  const float* W = blockIdx.z == 0 ? W0 : blockIdx.z == 1 ? W1 : blockIdx.z == 2 ? W2 : W3;
  unsigned short* D = blockIdx.z == 0 ? D0 : blockIdx.z == 1 ? D1 : blockIdx.z == 2 ? D2 : D3;
  __shared__ float tile[32][33];
  int n0 = blockIdx.x * 32, k0 = blockIdx.y * 32;
  int tx = threadIdx.x & 31, ty = threadIdx.x >> 5;  // 32 x 8
#pragma unroll
  for (int r = 0; r < 32; r += 8)
    tile[ty + r][tx] = W[(size_t)(k0 + ty + r) * 1024 + n0 + tx];
  __syncthreads();
#pragma unroll
  for (int r = 0; r < 32; r += 8)
    D[(size_t)(n0 + ty + r) * 1024 + k0 + tx] = f2bf(tile[tx][ty + r]);
}

// ---------------- 3) projection GEMM (m97-style) + rotary / V^T epilogue -----
// C[8192][1024] = A[8192][1024] @ Bt[1024][1024]^T ; 128x128 tile, BK=64.
// 4 waves in 2x2, each computes 64x64 via 4x4 MFMA accs.
__global__ __launch_bounds__(256) void proj_gemm(
    const unsigned short* __restrict__ XqBf, const unsigned short* __restrict__ XkvBf,
    const unsigned short* __restrict__ Wtq, const unsigned short* __restrict__ Wtk,
    const unsigned short* __restrict__ Wtv,
    unsigned short* __restrict__ Qb, unsigned short* __restrict__ Kb,
    unsigned short* __restrict__ Vt) {
  const int K = 1024;
  int z = blockIdx.z;
  const unsigned short* A  = (z == 0) ? XqBf : XkvBf;
  const unsigned short* Bt = (z == 0) ? Wtq : (z == 1) ? Wtk : Wtv;

  __shared__ __align__(16) unsigned short sA[128 * 64];  // [m][k] no pad (async dest)
  __shared__ __align__(16) unsigned short sB[128 * 64];  // [n][k]

  int tid = threadIdx.x;
  int lane = tid & 63, wave = tid >> 6;
  int quad = lane >> 4, l16 = lane & 15;
  int wm = wave & 1, wn = wave >> 1;
  int m_blk = blockIdx.y * 128, n_blk = blockIdx.x * 128;

  f4v acc[4][4] = {};
  // staging map: issue i stages rows i*32..i*32+31; thread t -> row i*32+(t>>3),
  // col (t&7)*8; LDS elem offset = i*2048 + t*8 (lane-contiguous, wave-uniform base).
  int srow = tid >> 3, scol = (tid & 7) * 8;
  const unsigned short* gA = A + (size_t)(m_blk + srow) * K + scol;
  const unsigned short* gB = Bt + (size_t)(n_blk + srow) * K + scol;

  for (int k0 = 0; k0 < K; k0 += 64) {
#pragma unroll
    for (int i = 0; i < 4; ++i) {
      ASYNC_CP16(gA + (size_t)i * 32 * K + k0, &sA[i * 2048 + tid * 8]);
      ASYNC_CP16(gB + (size_t)i * 32 * K + k0, &sB[i * 2048 + tid * 8]);
    }
    __syncthreads();  // drains vmcnt -> LDS ready
#pragma unroll
    for (int ks = 0; ks < 64; ks += 32) {
      s8v af[4], bf[4];
#pragma unroll
      for (int mt = 0; mt < 4; ++mt)
        af[mt] = *(const s8v*)&sA[(wm * 64 + mt * 16 + l16) * 64 + ks + quad * 8];
#pragma unroll
      for (int nt = 0; nt < 4; ++nt)
        bf[nt] = *(const s8v*)&sB[(wn * 64 + nt * 16 + l16) * 64 + ks + quad * 8];
#pragma unroll
      for (int mt = 0; mt < 4; ++mt)
#pragma unroll
        for (int nt = 0; nt < 4; ++nt)
          acc[mt][nt] = MFMA_BF16(af[mt], bf[nt], acc[mt][nt], 0, 0, 0);
    }
    __syncthreads();  // protect LDS before next overwrite
  }

  if (z < 2) {  // rotary epilogue -> Qb/Kb row-major [token][feat]
    unsigned short* Cb = (z == 0) ? Qb : Kb;
#pragma unroll
    for (int mt = 0; mt < 4; ++mt)
#pragma unroll
      for (int nt = 0; nt < 4; ++nt)
#pragma unroll
        for (int r = 0; r < 4; ++r) {
          int row = m_blk + wm * 64 + mt * 16 + quad * 4 + r;
          int col = n_blk + wn * 64 + nt * 16 + l16;
          float v = acc[mt][nt][r];
          float other = __shfl_xor(v, 1);  // pair partner: col^1 == lane^1
          int dh = col & 63;
          int tpos = row & 2047;
          float fi = (float)(dh >> 1) * (1.0f / 32.0f);
          float invf = __expf(-9.210340371976184f * fi);  // 10000^{-i/32}
          float ang = (float)tpos * invf;
          float s, c;
          __sincosf(ang, &s, &c);
          v = (dh & 1) ? (v * c + other * s) : (v * c - other * s);
          Cb[(size_t)row * 1024 + col] = f2bf(v);
        }
  } else {  // V: write transposed Vt[((b*16+h)*64+dh)][t], pack 4 consecutive t
#pragma unroll
    for (int mt = 0; mt < 4; ++mt)
#pragma unroll
      for (int nt = 0; nt < 4; ++nt) {
        int row0 = m_blk + wm * 64 + mt * 16 + quad * 4;  // t base (mult of 4)
        int col = n_blk + wn * 64 + nt * 16 + l16;        // feature
        int bb = row0 >> 11, t = row0 & 2047;
        int hh = col >> 6, dh = col & 63;
        ushort4 pk;
        pk.x = f2bf(acc[mt][nt][0]);
        pk.y = f2bf(acc[mt][nt][1]);
        pk.z = f2bf(acc[mt][nt][2]);
        pk.w = f2bf(acc[mt][nt][3]);
        *(ushort4*)&Vt[(((size_t)bb * 16 + hh) * 64 + dh) * 2048 + t] = pk;
      }
  }
}

// ---------------- 4) banded flash attention ---------------------------------
// grid (T/64=32, H=16, B=4), 4 waves; wave w owns q rows t0+16w..+15.
__global__ __launch_bounds__(256) void attn_kernel(
    const unsigned short* __restrict__ Qb, const unsigned short* __restrict__ Kb,
    const unsigned short* __restrict__ Vt, unsigned short* __restrict__ Ab) {
  const int T = 2048;
  int t0 = blockIdx.x * 64;
  int h = blockIdx.y;
  int b = blockIdx.z;
  int tid = threadIdx.x, lane = tid & 63, wave = tid >> 6;
  int quad = lane >> 4, l16 = lane & 15;

  __shared__ __align__(16) unsigned short sQ[64][72];      // [qrow][d]
  __shared__ __align__(16) unsigned short sK[64][72];      // [key][d]
  __shared__ __align__(16) unsigned short sV[64][72];      // [d][key]
  __shared__ __align__(16) unsigned short sP[4][16][72];   // per-wave P round-trip

  size_t base = ((size_t)b * T) * 1024 + (size_t)h * 64;
  size_t vbase = ((size_t)b * 16 + h) * 64 * 2048;
  int srow = tid >> 2, sseg = (tid & 3) * 16;

  {  // stage Q once
    const unsigned short* g = Qb + base + (size_t)(t0 + srow) * 1024 + sseg;
    *(uint4*)&sQ[srow][sseg] = *(const uint4*)g;
    *(uint4*)&sQ[srow][sseg + 8] = *(const uint4*)(g + 8);
  }
  __syncthreads();
  s8v aq0 = *(const s8v*)&sQ[wave * 16 + l16][quad * 8];
  s8v aq1 = *(const s8v*)&sQ[wave * 16 + l16][32 + quad * 8];

  f4v oacc[4] = {};
  float mrow[4], lrow[4];
#pragma unroll
  for (int r = 0; r < 4; ++r) { mrow[r] = -1e30f; lrow[r] = 0.0f; }

  int kv_lo = max(0, t0 - 256);
  int kv_hi = min(T, t0 + 64 + 256);  // both multiples of 64

  for (int kv0 = kv_lo; kv0 < kv_hi; kv0 += 64) {
    __syncthreads();  // protect previous tile's sK/sV reads
    {  // stage K row-major
      const unsigned short* g = Kb + base + (size_t)(kv0 + srow) * 1024 + sseg;
      *(uint4*)&sK[srow][sseg] = *(const uint4*)g;
      *(uint4*)&sK[srow][sseg + 8] = *(const uint4*)(g + 8);
    }
    {  // stage V from pre-transposed Vt: sV[d][key]
      const unsigned short* g = Vt + vbase + (size_t)srow * 2048 + kv0 + sseg;
      *(uint4*)&sV[srow][sseg] = *(const uint4*)g;
      *(uint4*)&sV[srow][sseg + 8] = *(const uint4*)(g + 8);
    }
    __syncthreads();

    // S = Q K^T  (16 rows x 64 keys per wave)
    f4v sacc[4];
#pragma unroll
    for (int nt = 0; nt < 4; ++nt) {
      s8v b0 = *(const s8v*)&sK[nt * 16 + l16][quad * 8];
      s8v b1 = *(const s8v*)&sK[nt * 16 + l16][32 + quad * 8];
      f4v zz = {};
      zz = MFMA_BF16(aq0, b0, zz, 0, 0, 0);
      sacc[nt] = MFMA_BF16(aq1, b1, zz, 0, 0, 0);
    }

    // scale + band mask + online softmax
    int qg = t0 + wave * 16 + quad * 4;  // +r
    float p[4][4];
    float mx[4];
#pragma unroll
    for (int r = 0; r < 4; ++r) mx[r] = -1e30f;
#pragma unroll
    for (int nt = 0; nt < 4; ++nt) {
      int kg = kv0 + nt * 16 + l16;
#pragma unroll
      for (int r = 0; r < 4; ++r) {
        int d = qg + r - kg;
        float s = sacc[nt][r] * 0.125f;
        s = (d <= 256 && d >= -256) ? s : -1e30f;
        p[nt][r] = s;
        mx[r] = fmaxf(mx[r], s);
      }
    }
#pragma unroll
    for (int off = 1; off < 16; off <<= 1)
#pragma unroll
      for (int r = 0; r < 4; ++r) mx[r] = fmaxf(mx[r], __shfl_xor(mx[r], off));

    float alpha[4], rsum[4];
#pragma unroll
    for (int r = 0; r < 4; ++r) {
      float mn = fmaxf(mrow[r], mx[r]);
      alpha[r] = __expf(mrow[r] - mn);
      mrow[r] = mn;
      rsum[r] = 0.0f;
    }
#pragma unroll
    for (int nt = 0; nt < 4; ++nt)
#pragma unroll
      for (int r = 0; r < 4; ++r) {
        float e = __expf(p[nt][r] - mrow[r]);
        p[nt][r] = e;
        rsum[r] += e;
      }
#pragma unroll
    for (int off = 1; off < 16; off <<= 1)
#pragma unroll
      for (int r = 0; r < 4; ++r) rsum[r] += __shfl_xor(rsum[r], off);
#pragma unroll
    for (int r = 0; r < 4; ++r) {
      lrow[r] = lrow[r] * alpha[r] + rsum[r];
#pragma unroll
      for (int dt = 0; dt < 4; ++dt) oacc[dt][r] *= alpha[r];
    }

    // P: C-layout -> LDS -> A-layout (per-wave)
#pragma unroll
    for (int nt = 0; nt < 4; ++nt)
#pragma unroll
      for (int r = 0; r < 4; ++r)
        sP[wave][quad * 4 + r][nt * 16 + l16] = f2bf(p[nt][r]);
    s8v pa0 = *(const s8v*)&sP[wave][l16][quad * 8];
    s8v pa1 = *(const s8v*)&sP[wave][l16][32 + quad * 8];

    // O += P V   (V as B operand from transposed sV)
#pragma unroll
    for (int dt = 0; dt < 4; ++dt) {
      s8v bv0 = *(const s8v*)&sV[dt * 16 + l16][quad * 8];
      s8v bv1 = *(const s8v*)&sV[dt * 16 + l16][32 + quad * 8];
      oacc[dt] = MFMA_BF16(pa0, bv0, oacc[dt], 0, 0, 0);
      oacc[dt] = MFMA_BF16(pa1, bv1, oacc[dt], 0, 0, 0);
    }
  }

  // normalize + store bf16
  float inv_l[4];
#pragma unroll
  for (int r = 0; r < 4; ++r) inv_l[r] = 1.0f / lrow[r];
#pragma unroll
  for (int dt = 0; dt < 4; ++dt)
#pragma unroll
    for (int r = 0; r < 4; ++r) {
      int row = t0 + wave * 16 + quad * 4 + r;
      int col = dt * 16 + l16;
      Ab[base + (size_t)row * 1024 + col] = f2bf(oacc[dt][r] * inv_l[r]);
    }
}

// ---------------- 5) output GEMM (m97-style): f32 out ------------------------
__global__ __launch_bounds__(256) void out_gemm(
    const unsigned short* __restrict__ A, const unsigned short* __restrict__ Bt,
    float* __restrict__ C) {
  const int K = 1024;
  __shared__ __align__(16) unsigned short sA[128 * 64];
  __shared__ __align__(16) unsigned short sB[128 * 64];

  int tid = threadIdx.x;
  int lane = tid & 63, wave = tid >> 6;
  int quad = lane >> 4, l16 = lane & 15;
  int wm = wave & 1, wn = wave >> 1;
  int m_blk = blockIdx.y * 128, n_blk = blockIdx.x * 128;

  f4v acc[4][4] = {};
  int srow = tid >> 3, scol = (tid & 7) * 8;
  const unsigned short* gA = A + (size_t)(m_blk + srow) * K + scol;
  const unsigned short* gB = Bt + (size_t)(n_blk + srow) * K + scol;

  for (int k0 = 0; k0 < K; k0 += 64) {
#pragma unroll
    for (int i = 0; i < 4; ++i) {
      ASYNC_CP16(gA + (size_t)i * 32 * K + k0, &sA[i * 2048 + tid * 8]);
      ASYNC_CP16(gB + (size_t)i * 32 * K + k0, &sB[i * 2048 + tid * 8]);
    }
    __syncthreads();
#pragma unroll
    for (int ks = 0; ks < 64; ks += 32) {
      s8v af[4], bf[4];
#pragma unroll
      for (int mt = 0; mt < 4; ++mt)
        af[mt] = *(const s8v*)&sA[(wm * 64 + mt * 16 + l16) * 64 + ks + quad * 8];
#pragma unroll
      for (int nt = 0; nt < 4; ++nt)
        bf[nt] = *(const s8v*)&sB[(wn * 64 + nt * 16 + l16) * 64 + ks + quad * 8];
#pragma unroll
      for (int mt = 0; mt < 4; ++mt)
#pragma unroll
        for (int nt = 0; nt < 4; ++nt)
          acc[mt][nt] = MFMA_BF16(af[mt], bf[nt], acc[mt][nt], 0, 0, 0);
    }
    __syncthreads();
  }

#pragma unroll
  for (int mt = 0; mt < 4; ++mt)
#pragma unroll
    for (int nt = 0; nt < 4; ++nt)
#pragma unroll
      for (int r = 0; r < 4; ++r) {
        int row = m_blk + wm * 64 + mt * 16 + quad * 4 + r;
        int col = n_blk + wn * 64 + nt * 16 + l16;
        C[(size_t)row * 1024 + col] = acc[mt][nt][r];
      }
}

// ---------------- launch -----------------------------------------------------
extern "C" void kernel_launch(void* const* d_in, const int* in_sizes, int n_in,
                              void* d_out, int out_size, void* d_ws, size_t ws_size,
                              hipStream_t stream) {
  const float* Xq  = (const float*)d_in[0];
  const float* Xkv = (const float*)d_in[1];
  const float* Wq  = (const float*)d_in[2];
  const float* Wk  = (const float*)d_in[3];
  const float* Wv  = (const float*)d_in[4];
  const float* Wo  = (const float*)d_in[5];
  float* out = (float*)d_out;

  char* ws = (char*)d_ws;
  const size_t MB = 1ull << 20;
  unsigned short* XqBf  = (unsigned short*)(ws + 0 * MB);   // 16 MiB
  unsigned short* XkvBf = (unsigned short*)(ws + 16 * MB);  // 16 MiB
  unsigned short* Wtq   = (unsigned short*)(ws + 32 * MB);  // 2 MiB each
  unsigned short* Wtk   = (unsigned short*)(ws + 34 * MB);
  unsigned short* Wtv   = (unsigned short*)(ws + 36 * MB);
  unsigned short* Wto   = (unsigned short*)(ws + 38 * MB);
  unsigned short* Qb    = (unsigned short*)(ws + 40 * MB);  // 16 MiB
  unsigned short* Kb    = (unsigned short*)(ws + 56 * MB);  // 16 MiB
  unsigned short* Vt    = (unsigned short*)(ws + 72 * MB);  // 16 MiB (transposed V)
  unsigned short* Ab    = XqBf;  // reuse: XqBf dead after proj_gemm

  cvt_kernel<<<8192, 256, 0, stream>>>(Xq, XqBf);
  cvt_kernel<<<8192, 256, 0, stream>>>(Xkv, XkvBf);
  wtrans_kernel<<<dim3(32, 32, 4), 256, 0, stream>>>(Wq, Wk, Wv, Wo, Wtq, Wtk, Wtv, Wto);
  proj_gemm<<<dim3(8, 64, 3), 256, 0, stream>>>(XqBf, XkvBf, Wtq, Wtk, Wtv, Qb, Kb, Vt);
  attn_kernel<<<dim3(32, 16, 4), 256, 0, stream>>>(Qb, Kb, Vt, Ab);
  out_gemm<<<dim3(8, 64), 256, 0, stream>>>(Ab, Wto, out);
}

// Round 3
// 293.804 us; speedup vs baseline: 1.1551x; 1.0938x over previous
//
#include <hip/hip_runtime.h>

// ---------------------------------------------------------------------------
// MultiHeadDotProductAttention: rotary + sliding-window (|i-j|<=256) MHA
// B=4 T=2048 E=1024 H=16x64=1024.  bf16 MFMA (16x16x32) for all matmuls.
//
// R3: (a) m-major grid (x=m) so same-A blocks share an XCD's L2 (round-robin
//     linear%8 = m%8);  (b) XOR-swizzled LDS for async staging (kills the
//     ~16-way ds_read_b128 bank conflicts of the unpadded layout);
//     (c) attn: 128-row q-blocks, sQ reused as sP, register prefetch of the
//     next K/V tile, wave-level skip of fully-masked tiles.
//
// Verified layout facts (learn_hip m89/m91/m120):
//   mfma_f32_16x16x32_bf16: A[m=lane&15][k=(lane>>4)*8+j], B[k=...][n=lane&15]
//   C/D: col=lane&15, row=(lane>>4)*4+reg
// global_load_lds: LDS dest is wave-uniform base + lane*16 (m104/m108);
// swizzle is applied by permuting the per-lane GLOBAL source granule.
// ---------------------------------------------------------------------------

typedef __attribute__((ext_vector_type(8))) short s8v;    // 8 x bf16
typedef __attribute__((ext_vector_type(4))) float f4v;    // MFMA acc

#define MFMA_BF16 __builtin_amdgcn_mfma_f32_16x16x32_bf16

#define ASYNC_CP16(g, l)                                             \
  __builtin_amdgcn_global_load_lds(                                  \
      (const __attribute__((address_space(1))) void*)(g),            \
      (__attribute__((address_space(3))) void*)(l), 16, 0, 0)

// swizzled LDS element offset for (row, 16B-granule g) in a [*][64] tile
#define SWZ(row, g) ((row) * 64 + ((((g) ^ ((row) & 7))) * 8))

__device__ __forceinline__ unsigned short f2bf(float f) {
  union { float f; unsigned int u; } v; v.f = f;
  unsigned int r = (v.u + 0x7fffu + ((v.u >> 16) & 1u)) >> 16;  // RNE
  return (unsigned short)r;
}

// ---------------- 1) f32 -> bf16 cast (both inputs, one dispatch) -----------
__global__ __launch_bounds__(256) void cvt2_kernel(
    const float* __restrict__ s0, const float* __restrict__ s1,
    unsigned short* __restrict__ d0, unsigned short* __restrict__ d1) {
  int g = blockIdx.x;
  const float* src = (g < 8192) ? s0 : s1;
  unsigned short* dst = (g < 8192) ? d0 : d1;
  int i = ((g & 8191) * 256 + threadIdx.x) * 4;
  float4 v = *(const float4*)(src + i);
  ushort4 o;
  o.x = f2bf(v.x); o.y = f2bf(v.y); o.z = f2bf(v.z); o.w = f2bf(v.w);
  *(ushort4*)(dst + i) = o;
}

// ---------------- 2) weight transpose + cast: Wt[n][k] = bf16(W[k][n]) ------
__global__ __launch_bounds__(256) void wtrans_kernel(
    const float* __restrict__ W0, const float* __restrict__ W1,
    const float* __restrict__ W2, const float* __restrict__ W3,
    unsigned short* __restrict__ D0, unsigned short* __restrict__ D1,
    unsigned short* __restrict__ D2, unsigned short* __restrict__ D3) {
  const float* W = blockIdx.z == 0 ? W0 : blockIdx.z == 1 ? W1 : blockIdx.z == 2 ? W2 : W3;
  unsigned short* D = blockIdx.z == 0 ? D0 : blockIdx.z == 1 ? D1 : blockIdx.z == 2 ? D2 : D3;
  __shared__ float tile[32][33];
  int n0 = blockIdx.x * 32, k0 = blockIdx.y * 32;
  int tx = threadIdx.x & 31, ty = threadIdx.x >> 5;  // 32 x 8
#pragma unroll
  for (int r = 0; r < 32; r += 8)
    tile[ty + r][tx] = W[(size_t)(k0 + ty + r) * 1024 + n0 + tx];
  __syncthreads();
#pragma unroll
  for (int r = 0; r < 32; r += 8)
    D[(size_t)(n0 + ty + r) * 1024 + k0 + tx] = f2bf(tile[tx][ty + r]);
}

// ---------------- 3) projection GEMM (m97-style, swizzled, m-major) ---------
// grid (64=m, 8=n, 3=z).  128x128 tile, BK=64; 4 waves x 4x4 MFMA accs.
__global__ __launch_bounds__(256) void proj_gemm(
    const unsigned short* __restrict__ XqBf, const unsigned short* __restrict__ XkvBf,
    const unsigned short* __restrict__ Wtq, const unsigned short* __restrict__ Wtk,
    const unsigned short* __restrict__ Wtv,
    unsigned short* __restrict__ Qb, unsigned short* __restrict__ Kb,
    unsigned short* __restrict__ Vt) {
  const int K = 1024;
  int z = blockIdx.z;
  const unsigned short* A  = (z == 0) ? XqBf : XkvBf;
  const unsigned short* Bt = (z == 0) ? Wtq : (z == 1) ? Wtk : Wtv;

  __shared__ __align__(16) unsigned short sA[128 * 64];
  __shared__ __align__(16) unsigned short sB[128 * 64];

  int tid = threadIdx.x;
  int lane = tid & 63, wave = tid >> 6;
  int quad = lane >> 4, l16 = lane & 15;
  int wm = wave & 1, wn = wave >> 1;
  int m_blk = blockIdx.x * 128, n_blk = blockIdx.y * 128;  // m-major!

  f4v acc[4][4] = {};
  // staging: issue i stages rows i*32..+31; thread t -> row i*32+(t>>3),
  // global granule (t&7)^((t>>3)&7); LDS elem offset i*2048 + t*8.
  int srow = tid >> 3, sg = (tid & 7) ^ (srow & 7);
  const unsigned short* gA = A + (size_t)(m_blk + srow) * K + sg * 8;
  const unsigned short* gB = Bt + (size_t)(n_blk + srow) * K + sg * 8;

  for (int k0 = 0; k0 < K; k0 += 64) {
#pragma unroll
    for (int i = 0; i < 4; ++i) {
      ASYNC_CP16(gA + (size_t)i * 32 * K + k0, &sA[i * 2048 + tid * 8]);
      ASYNC_CP16(gB + (size_t)i * 32 * K + k0, &sB[i * 2048 + tid * 8]);
    }
    __syncthreads();
#pragma unroll
    for (int ks = 0; ks < 64; ks += 32) {
      s8v af[4], bf[4];
#pragma unroll
      for (int mt = 0; mt < 4; ++mt)
        af[mt] = *(const s8v*)&sA[SWZ(wm * 64 + mt * 16 + l16, quad + (ks >> 3))];
#pragma unroll
      for (int nt = 0; nt < 4; ++nt)
        bf[nt] = *(const s8v*)&sB[SWZ(wn * 64 + nt * 16 + l16, quad + (ks >> 3))];
#pragma unroll
      for (int mt = 0; mt < 4; ++mt)
#pragma unroll
        for (int nt = 0; nt < 4; ++nt)
          acc[mt][nt] = MFMA_BF16(af[mt], bf[nt], acc[mt][nt], 0, 0, 0);
    }
    __syncthreads();
  }

  if (z < 2) {  // rotary epilogue -> Qb/Kb row-major [token][feat]
    unsigned short* Cb = (z == 0) ? Qb : Kb;
#pragma unroll
    for (int mt = 0; mt < 4; ++mt)
#pragma unroll
      for (int nt = 0; nt < 4; ++nt)
#pragma unroll
        for (int r = 0; r < 4; ++r) {
          int row = m_blk + wm * 64 + mt * 16 + quad * 4 + r;
          int col = n_blk + wn * 64 + nt * 16 + l16;
          float v = acc[mt][nt][r];
          float other = __shfl_xor(v, 1);  // pair partner: col^1 == lane^1
          int dh = col & 63;
          int tpos = row & 2047;
          float fi = (float)(dh >> 1) * (1.0f / 32.0f);
          float invf = __expf(-9.210340371976184f * fi);  // 10000^{-i/32}
          float ang = (float)tpos * invf;
          float s, c;
          __sincosf(ang, &s, &c);
          v = (dh & 1) ? (v * c + other * s) : (v * c - other * s);
          Cb[(size_t)row * 1024 + col] = f2bf(v);
        }
  } else {  // V: write transposed Vt[((b*16+h)*64+dh)][t], pack 4 consecutive t
#pragma unroll
    for (int mt = 0; mt < 4; ++mt)
#pragma unroll
      for (int nt = 0; nt < 4; ++nt) {
        int row0 = m_blk + wm * 64 + mt * 16 + quad * 4;  // t base (mult of 4)
        int col = n_blk + wn * 64 + nt * 16 + l16;        // feature
        int bb = row0 >> 11, t = row0 & 2047;
        int hh = col >> 6, dh = col & 63;
        ushort4 pk;
        pk.x = f2bf(acc[mt][nt][0]);
        pk.y = f2bf(acc[mt][nt][1]);
        pk.z = f2bf(acc[mt][nt][2]);
        pk.w = f2bf(acc[mt][nt][3]);
        *(ushort4*)&Vt[(((size_t)bb * 16 + hh) * 64 + dh) * 2048 + t] = pk;
      }
  }
}

// ---------------- 4) banded flash attention (128-row q-blocks) --------------
// grid (T/128=16, H=16, B=4); wave w owns q rows t0+32w..+31 (2 m-frags).
__global__ __launch_bounds__(256) void attn_kernel(
    const unsigned short* __restrict__ Qb, const unsigned short* __restrict__ Kb,
    const unsigned short* __restrict__ Vt, unsigned short* __restrict__ Ab) {
  const int T = 2048;
  int t0 = blockIdx.x * 128;
  int h = blockIdx.y, b = blockIdx.z;
  int tid = threadIdx.x, lane = tid & 63, wave = tid >> 6;
  int quad = lane >> 4, l16 = lane & 15;

  __shared__ __align__(16) unsigned short sQP[128][72];  // Q frags, then P
  __shared__ __align__(16) unsigned short sK[64][72];    // [key][d]
  __shared__ __align__(16) unsigned short sV[64][72];    // [d][key]

  size_t base = ((size_t)b * T) * 1024 + (size_t)h * 64;
  size_t vbase = ((size_t)b * 16 + h) * 64 * 2048;

  {  // Q staging: thread t -> row t>>1 (wave-local rows!), cols (t&1)*32..+31
    int qr = tid >> 1, qc = (tid & 1) * 32;
    const unsigned short* g = Qb + base + (size_t)(t0 + qr) * 1024 + qc;
#pragma unroll
    for (int j = 0; j < 4; ++j)
      *(uint4*)&sQP[qr][qc + j * 8] = *(const uint4*)(g + j * 8);
  }
  // rows wave*32..+31 are written and read only by this wave: no barrier.
  s8v aq[2][2];
#pragma unroll
  for (int f = 0; f < 2; ++f) {
    aq[f][0] = *(const s8v*)&sQP[wave * 32 + f * 16 + l16][quad * 8];
    aq[f][1] = *(const s8v*)&sQP[wave * 32 + f * 16 + l16][32 + quad * 8];
  }

  f4v oacc[2][4] = {};
  float mrow[2][4], lrow[2][4];
#pragma unroll
  for (int f = 0; f < 2; ++f)
#pragma unroll
    for (int r = 0; r < 4; ++r) { mrow[f][r] = -1e30f; lrow[f][r] = 0.0f; }

  int kv_lo = max(0, t0 - 256);
  int kv_hi = min(T, t0 + 128 + 256);
  int ntiles = (kv_hi - kv_lo) >> 6;

  int srow = tid >> 2, sseg = (tid & 3) * 16;
  const unsigned short* gK = Kb + base + (size_t)(kv_lo + srow) * 1024 + sseg;
  const unsigned short* gV = Vt + vbase + (size_t)srow * 2048 + kv_lo + sseg;
  uint4 rk0 = *(const uint4*)gK, rk1 = *(const uint4*)(gK + 8);
  uint4 rv0 = *(const uint4*)gV, rv1 = *(const uint4*)(gV + 8);

  int qlo = t0 + wave * 32;  // wave-uniform

  for (int it = 0; it < ntiles; ++it) {
    int kv0 = kv_lo + (it << 6);
    __syncthreads();  // previous tile's sK/sV reads complete
    *(uint4*)&sK[srow][sseg] = rk0;
    *(uint4*)&sK[srow][sseg + 8] = rk1;
    *(uint4*)&sV[srow][sseg] = rv0;
    *(uint4*)&sV[srow][sseg + 8] = rv1;
    __syncthreads();  // sK/sV ready
    if (it + 1 < ntiles) {  // register prefetch overlaps compute
      const unsigned short* nK = gK + (size_t)(it + 1) * 64 * 1024;
      const unsigned short* nV = gV + (it + 1) * 64;
      rk0 = *(const uint4*)nK; rk1 = *(const uint4*)(nK + 8);
      rv0 = *(const uint4*)nV; rv1 = *(const uint4*)(nV + 8);
    }
    // wave-level skip of fully-masked (wave, tile) pairs; barriers are at
    // loop top so `continue` is barrier-safe.  Alignment analysis guarantees
    // every row of an active tile has >=1 unmasked key.
    if (kv0 > qlo + 31 + 256 || kv0 + 63 < qlo - 256) continue;

#pragma unroll
    for (int f = 0; f < 2; ++f) {
      // S = Q K^T (16 rows x 64 keys)
      f4v sacc[4];
#pragma unroll
      for (int nt = 0; nt < 4; ++nt) {
        s8v b0 = *(const s8v*)&sK[nt * 16 + l16][quad * 8];
        s8v b1 = *(const s8v*)&sK[nt * 16 + l16][32 + quad * 8];
        f4v zz = {};
        zz = MFMA_BF16(aq[f][0], b0, zz, 0, 0, 0);
        sacc[nt] = MFMA_BF16(aq[f][1], b1, zz, 0, 0, 0);
      }

      int qg = qlo + f * 16 + quad * 4;  // +r
      float p[4][4];
      float mx[4];
#pragma unroll
      for (int r = 0; r < 4; ++r) mx[r] = -1e30f;
#pragma unroll
      for (int nt = 0; nt < 4; ++nt) {
        int kg = kv0 + nt * 16 + l16;
#pragma unroll
        for (int r = 0; r < 4; ++r) {
          int d = qg + r - kg;
          float s = sacc[nt][r] * 0.125f;
          s = (d <= 256 && d >= -256) ? s : -1e30f;
          p[nt][r] = s;
          mx[r] = fmaxf(mx[r], s);
        }
      }
#pragma unroll
      for (int off = 1; off < 16; off <<= 1)
#pragma unroll
        for (int r = 0; r < 4; ++r) mx[r] = fmaxf(mx[r], __shfl_xor(mx[r], off));

      float alpha[4], rsum[4];
#pragma unroll
      for (int r = 0; r < 4; ++r) {
        float mn = fmaxf(mrow[f][r], mx[r]);
        alpha[r] = __expf(mrow[f][r] - mn);
        mrow[f][r] = mn;
        rsum[r] = 0.0f;
      }
#pragma unroll
      for (int nt = 0; nt < 4; ++nt)
#pragma unroll
        for (int r = 0; r < 4; ++r) {
          float e = __expf(p[nt][r] - mrow[f][r]);
          p[nt][r] = e;
          rsum[r] += e;
        }
#pragma unroll
      for (int off = 1; off < 16; off <<= 1)
#pragma unroll
        for (int r = 0; r < 4; ++r) rsum[r] += __shfl_xor(rsum[r], off);
#pragma unroll
      for (int r = 0; r < 4; ++r) {
        lrow[f][r] = lrow[f][r] * alpha[r] + rsum[r];
#pragma unroll
        for (int dt = 0; dt < 4; ++dt) oacc[f][dt][r] *= alpha[r];
      }

      // P: C-layout -> LDS (own wave's sQP region) -> A-layout
#pragma unroll
      for (int nt = 0; nt < 4; ++nt)
#pragma unroll
        for (int r = 0; r < 4; ++r)
          sQP[wave * 32 + f * 16 + quad * 4 + r][nt * 16 + l16] = f2bf(p[nt][r]);
      s8v pa0 = *(const s8v*)&sQP[wave * 32 + f * 16 + l16][quad * 8];
      s8v pa1 = *(const s8v*)&sQP[wave * 32 + f * 16 + l16][32 + quad * 8];

      // O += P V
#pragma unroll
      for (int dt = 0; dt < 4; ++dt) {
        s8v bv0 = *(const s8v*)&sV[dt * 16 + l16][quad * 8];
        s8v bv1 = *(const s8v*)&sV[dt * 16 + l16][32 + quad * 8];
        oacc[f][dt] = MFMA_BF16(pa0, bv0, oacc[f][dt], 0, 0, 0);
        oacc[f][dt] = MFMA_BF16(pa1, bv1, oacc[f][dt], 0, 0, 0);
      }
    }
  }

  // normalize + store bf16
#pragma unroll
  for (int f = 0; f < 2; ++f) {
    float inv_l[4];
#pragma unroll
    for (int r = 0; r < 4; ++r) inv_l[r] = 1.0f / lrow[f][r];
#pragma unroll
    for (int dt = 0; dt < 4; ++dt)
#pragma unroll
      for (int r = 0; r < 4; ++r) {
        int row = t0 + wave * 32 + f * 16 + quad * 4 + r;
        int col = dt * 16 + l16;
        Ab[base + (size_t)row * 1024 + col] = f2bf(oacc[f][dt][r] * inv_l[r]);
      }
  }
}

// ---------------- 5) output GEMM (swizzled, m-major): f32 out ---------------
__global__ __launch_bounds__(256) void out_gemm(
    const unsigned short* __restrict__ A, const unsigned short* __restrict__ Bt,
    float* __restrict__ C) {
  const int K = 1024;
  __shared__ __align__(16) unsigned short sA[128 * 64];
  __shared__ __align__(16) unsigned short sB[128 * 64];

  int tid = threadIdx.x;
  int lane = tid & 63, wave = tid >> 6;
  int quad = lane >> 4, l16 = lane & 15;
  int wm = wave & 1, wn = wave >> 1;
  int m_blk = blockIdx.x * 128, n_blk = blockIdx.y * 128;  // m-major!

  f4v acc[4][4] = {};
  int srow = tid >> 3, sg = (tid & 7) ^ (srow & 7);
  const unsigned short* gA = A + (size_t)(m_blk + srow) * K + sg * 8;
  const unsigned short* gB = Bt + (size_t)(n_blk + srow) * K + sg * 8;

  for (int k0 = 0; k0 < K; k0 += 64) {
#pragma unroll
    for (int i = 0; i < 4; ++i) {
      ASYNC_CP16(gA + (size_t)i * 32 * K + k0, &sA[i * 2048 + tid * 8]);
      ASYNC_CP16(gB + (size_t)i * 32 * K + k0, &sB[i * 2048 + tid * 8]);
    }
    __syncthreads();
#pragma unroll
    for (int ks = 0; ks < 64; ks += 32) {
      s8v af[4], bf[4];
#pragma unroll
      for (int mt = 0; mt < 4; ++mt)
        af[mt] = *(const s8v*)&sA[SWZ(wm * 64 + mt * 16 + l16, quad + (ks >> 3))];
#pragma unroll
      for (int nt = 0; nt < 4; ++nt)
        bf[nt] = *(const s8v*)&sB[SWZ(wn * 64 + nt * 16 + l16, quad + (ks >> 3))];
#pragma unroll
      for (int mt = 0; mt < 4; ++mt)
#pragma unroll
        for (int nt = 0; nt < 4; ++nt)
          acc[mt][nt] = MFMA_BF16(af[mt], bf[nt], acc[mt][nt], 0, 0, 0);
    }
    __syncthreads();
  }

#pragma unroll
  for (int mt = 0; mt < 4; ++mt)
#pragma unroll
    for (int nt = 0; nt < 4; ++nt)
#pragma unroll
      for (int r = 0; r < 4; ++r) {
        int row = m_blk + wm * 64 + mt * 16 + quad * 4 + r;
        int col = n_blk + wn * 64 + nt * 16 + l16;
        C[(size_t)row * 1024 + col] = acc[mt][nt][r];
      }
}

// ---------------- launch -----------------------------------------------------
extern "C" void kernel_launch(void* const* d_in, const int* in_sizes, int n_in,
                              void* d_out, int out_size, void* d_ws, size_t ws_size,
                              hipStream_t stream) {
  const float* Xq  = (const float*)d_in[0];
  const float* Xkv = (const float*)d_in[1];
  const float* Wq  = (const float*)d_in[2];
  const float* Wk  = (const float*)d_in[3];
  const float* Wv  = (const float*)d_in[4];
  const float* Wo  = (const float*)d_in[5];
  float* out = (float*)d_out;

  char* ws = (char*)d_ws;
  const size_t MB = 1ull << 20;
  unsigned short* XqBf  = (unsigned short*)(ws + 0 * MB);   // 16 MiB
  unsigned short* XkvBf = (unsigned short*)(ws + 16 * MB);  // 16 MiB
  unsigned short* Wtq   = (unsigned short*)(ws + 32 * MB);  // 2 MiB each
  unsigned short* Wtk   = (unsigned short*)(ws + 34 * MB);
  unsigned short* Wtv   = (unsigned short*)(ws + 36 * MB);
  unsigned short* Wto   = (unsigned short*)(ws + 38 * MB);
  unsigned short* Qb    = (unsigned short*)(ws + 40 * MB);  // 16 MiB
  unsigned short* Kb    = (unsigned short*)(ws + 56 * MB);  // 16 MiB
  unsigned short* Vt    = (unsigned short*)(ws + 72 * MB);  // 16 MiB (transposed V)
  unsigned short* Ab    = XqBf;  // reuse: XqBf dead after proj_gemm

  cvt2_kernel<<<16384, 256, 0, stream>>>(Xq, Xkv, XqBf, XkvBf);
  wtrans_kernel<<<dim3(32, 32, 4), 256, 0, stream>>>(Wq, Wk, Wv, Wo, Wtq, Wtk, Wtv, Wto);
  proj_gemm<<<dim3(64, 8, 3), 256, 0, stream>>>(XqBf, XkvBf, Wtq, Wtk, Wtv, Qb, Kb, Vt);
  attn_kernel<<<dim3(16, 16, 4), 256, 0, stream>>>(Qb, Kb, Vt, Ab);
  out_gemm<<<dim3(64, 8), 256, 0, stream>>>(Ab, Wto, out);
}

// Round 4
// 259.018 us; speedup vs baseline: 1.3102x; 1.1343x over previous
//
#include <hip/hip_runtime.h>
#include <hip/hip_bf16.h>

// ---------------------------------------------------------------------------
// MultiHeadDotProductAttention: rotary + sliding-window (|i-j|<=256) MHA
// B=4 T=2048 E=1024 H=16x64=1024.  bf16 MFMA (16x16x32) for all matmuls.
//
// R4: attn computes S^T = K*Q^T (operand swap) so each lane owns ONE q-row's
//     scores: row softmax = in-lane reduce + 2 cross-quad shfls (was 32
//     shfls); P^T packs to LDS as 4x ds_write_b64 (was 16x u16); O^T epilogue
//     stores 8B vectors.  1/sqrt(d) folded into Q (exact 2^-3 in bf16).
//     Mask skipped on interior (fully-unmasked) tiles.
//
// Verified layout facts (learn_hip m89/m91/m120):
//   mfma_f32_16x16x32_bf16: A[m=lane&15][k=(lane>>4)*8+j], B[k=...][n=lane&15]
//   C/D: col=lane&15, row=(lane>>4)*4+reg
// ---------------------------------------------------------------------------

typedef __attribute__((ext_vector_type(8))) short s8v;    // 8 x bf16
typedef __attribute__((ext_vector_type(4))) float f4v;    // MFMA acc

#define MFMA_BF16 __builtin_amdgcn_mfma_f32_16x16x32_bf16

#define ASYNC_CP16(g, l)                                             \
  __builtin_amdgcn_global_load_lds(                                  \
      (const __attribute__((address_space(1))) void*)(g),            \
      (__attribute__((address_space(3))) void*)(l), 16, 0, 0)

// swizzled LDS element offset for (row, 16B-granule g) in a [*][64] tile
#define SWZ(row, g) ((row) * 64 + ((((g) ^ ((row) & 7))) * 8))

__device__ __forceinline__ unsigned short f2bf(float f) {
  union { float f; unsigned int u; } v; v.f = f;
  unsigned int r = (v.u + 0x7fffu + ((v.u >> 16) & 1u)) >> 16;  // RNE
  return (unsigned short)r;
}

__device__ __forceinline__ unsigned int pack_bf16(float a, float b) {
  union { __hip_bfloat162 h; unsigned int u; } cv;
  cv.h = __float22bfloat162_rn(make_float2(a, b));
  return cv.u;
}

// ---------------- 1) f32 -> bf16 cast (both inputs, one dispatch) -----------
__global__ __launch_bounds__(256) void cvt2_kernel(
    const float* __restrict__ s0, const float* __restrict__ s1,
    unsigned short* __restrict__ d0, unsigned short* __restrict__ d1) {
  int g = blockIdx.x;
  const float* src = (g < 8192) ? s0 : s1;
  unsigned short* dst = (g < 8192) ? d0 : d1;
  int i = ((g & 8191) * 256 + threadIdx.x) * 4;
  float4 v = *(const float4*)(src + i);
  ushort4 o;
  o.x = f2bf(v.x); o.y = f2bf(v.y); o.z = f2bf(v.z); o.w = f2bf(v.w);
  *(ushort4*)(dst + i) = o;
}

// ---------------- 2) weight transpose + cast: Wt[n][k] = bf16(W[k][n]) ------
__global__ __launch_bounds__(256) void wtrans_kernel(
    const float* __restrict__ W0, const float* __restrict__ W1,
    const float* __restrict__ W2, const float* __restrict__ W3,
    unsigned short* __restrict__ D0, unsigned short* __restrict__ D1,
    unsigned short* __restrict__ D2, unsigned short* __restrict__ D3) {
  const float* W = blockIdx.z == 0 ? W0 : blockIdx.z == 1 ? W1 : blockIdx.z == 2 ? W2 : W3;
  unsigned short* D = blockIdx.z == 0 ? D0 : blockIdx.z == 1 ? D1 : blockIdx.z == 2 ? D2 : D3;
  __shared__ float tile[32][33];
  int n0 = blockIdx.x * 32, k0 = blockIdx.y * 32;
  int tx = threadIdx.x & 31, ty = threadIdx.x >> 5;  // 32 x 8
#pragma unroll
  for (int r = 0; r < 32; r += 8)
    tile[ty + r][tx] = W[(size_t)(k0 + ty + r) * 1024 + n0 + tx];
  __syncthreads();
#pragma unroll
  for (int r = 0; r < 32; r += 8)
    D[(size_t)(n0 + ty + r) * 1024 + k0 + tx] = f2bf(tile[tx][ty + r]);
}

// ---------------- 3) projection GEMM (m97-style, swizzled, m-major) ---------
// grid (64=m, 8=n, 3=z).  128x128 tile, BK=64; 4 waves x 4x4 MFMA accs.
// z==0 (Q) additionally scales by 1/8 (softmax logit scale, exact in bf16).
__global__ __launch_bounds__(256) void proj_gemm(
    const unsigned short* __restrict__ XqBf, const unsigned short* __restrict__ XkvBf,
    const unsigned short* __restrict__ Wtq, const unsigned short* __restrict__ Wtk,
    const unsigned short* __restrict__ Wtv,
    unsigned short* __restrict__ Qb, unsigned short* __restrict__ Kb,
    unsigned short* __restrict__ Vt) {
  const int K = 1024;
  int z = blockIdx.z;
  const unsigned short* A  = (z == 0) ? XqBf : XkvBf;
  const unsigned short* Bt = (z == 0) ? Wtq : (z == 1) ? Wtk : Wtv;

  __shared__ __align__(16) unsigned short sA[128 * 64];
  __shared__ __align__(16) unsigned short sB[128 * 64];

  int tid = threadIdx.x;
  int lane = tid & 63, wave = tid >> 6;
  int quad = lane >> 4, l16 = lane & 15;
  int wm = wave & 1, wn = wave >> 1;
  int m_blk = blockIdx.x * 128, n_blk = blockIdx.y * 128;  // m-major!

  f4v acc[4][4] = {};
  int srow = tid >> 3, sg = (tid & 7) ^ (srow & 7);
  const unsigned short* gA = A + (size_t)(m_blk + srow) * K + sg * 8;
  const unsigned short* gB = Bt + (size_t)(n_blk + srow) * K + sg * 8;

  for (int k0 = 0; k0 < K; k0 += 64) {
#pragma unroll
    for (int i = 0; i < 4; ++i) {
      ASYNC_CP16(gA + (size_t)i * 32 * K + k0, &sA[i * 2048 + tid * 8]);
      ASYNC_CP16(gB + (size_t)i * 32 * K + k0, &sB[i * 2048 + tid * 8]);
    }
    __syncthreads();
#pragma unroll
    for (int ks = 0; ks < 64; ks += 32) {
      s8v af[4], bf[4];
#pragma unroll
      for (int mt = 0; mt < 4; ++mt)
        af[mt] = *(const s8v*)&sA[SWZ(wm * 64 + mt * 16 + l16, quad + (ks >> 3))];
#pragma unroll
      for (int nt = 0; nt < 4; ++nt)
        bf[nt] = *(const s8v*)&sB[SWZ(wn * 64 + nt * 16 + l16, quad + (ks >> 3))];
#pragma unroll
      for (int mt = 0; mt < 4; ++mt)
#pragma unroll
        for (int nt = 0; nt < 4; ++nt)
          acc[mt][nt] = MFMA_BF16(af[mt], bf[nt], acc[mt][nt], 0, 0, 0);
    }
    __syncthreads();
  }

  if (z < 2) {  // rotary epilogue -> Qb/Kb row-major [token][feat]
    unsigned short* Cb = (z == 0) ? Qb : Kb;
    float post = (z == 0) ? 0.125f : 1.0f;  // fold 1/sqrt(64) into Q (exact)
#pragma unroll
    for (int mt = 0; mt < 4; ++mt)
#pragma unroll
      for (int nt = 0; nt < 4; ++nt)
#pragma unroll
        for (int r = 0; r < 4; ++r) {
          int row = m_blk + wm * 64 + mt * 16 + quad * 4 + r;
          int col = n_blk + wn * 64 + nt * 16 + l16;
          float v = acc[mt][nt][r];
          float other = __shfl_xor(v, 1);  // pair partner: col^1 == lane^1
          int dh = col & 63;
          int tpos = row & 2047;
          float fi = (float)(dh >> 1) * (1.0f / 32.0f);
          float invf = __expf(-9.210340371976184f * fi);  // 10000^{-i/32}
          float ang = (float)tpos * invf;
          float s, c;
          __sincosf(ang, &s, &c);
          v = (dh & 1) ? (v * c + other * s) : (v * c - other * s);
          Cb[(size_t)row * 1024 + col] = f2bf(v * post);
        }
  } else {  // V: write transposed Vt[((b*16+h)*64+dh)][t], pack 4 consecutive t
#pragma unroll
    for (int mt = 0; mt < 4; ++mt)
#pragma unroll
      for (int nt = 0; nt < 4; ++nt) {
        int row0 = m_blk + wm * 64 + mt * 16 + quad * 4;  // t base (mult of 4)
        int col = n_blk + wn * 64 + nt * 16 + l16;        // feature
        int bb = row0 >> 11, t = row0 & 2047;
        int hh = col >> 6, dh = col & 63;
        ushort4 pk;
        pk.x = f2bf(acc[mt][nt][0]);
        pk.y = f2bf(acc[mt][nt][1]);
        pk.z = f2bf(acc[mt][nt][2]);
        pk.w = f2bf(acc[mt][nt][3]);
        *(ushort4*)&Vt[(((size_t)bb * 16 + hh) * 64 + dh) * 2048 + t] = pk;
      }
  }
}

// ---------------- 4) banded flash attention (S^T orientation) ---------------
// grid (T/128=16, H=16, B=4); wave w owns q rows t0+32w..+31 (2 f-frags).
// S^T = K*Q^T: lane l16 = q row; 16 scores/lane are one row's -> cheap softmax.
__global__ __launch_bounds__(256, 4) void attn_kernel(
    const unsigned short* __restrict__ Qb, const unsigned short* __restrict__ Kb,
    const unsigned short* __restrict__ Vt, unsigned short* __restrict__ Ab) {
  const int T = 2048;
  int t0 = blockIdx.x * 128;
  int h = blockIdx.y, b = blockIdx.z;
  int tid = threadIdx.x, lane = tid & 63, wave = tid >> 6;
  int quad = lane >> 4, l16 = lane & 15;

  __shared__ __align__(16) unsigned short sK[64][72];     // [key][d]
  __shared__ __align__(16) unsigned short sV[64][72];     // [d][key]
  __shared__ __align__(16) unsigned short sP[4][16][72];  // [wave][qrow][key]

  size_t base = ((size_t)b * T) * 1024 + (size_t)h * 64;
  size_t vbase = ((size_t)b * 16 + h) * 64 * 2048;
  int qlo = t0 + wave * 32;  // wave-uniform

  // Q B-fragments straight from global (B[k=quad*8+j][n=l16]); Q pre-scaled.
  s8v bq[2][2];
#pragma unroll
  for (int f = 0; f < 2; ++f) {
    const unsigned short* g = Qb + base + (size_t)(qlo + f * 16 + l16) * 1024;
    bq[f][0] = *(const s8v*)(g + quad * 8);
    bq[f][1] = *(const s8v*)(g + 32 + quad * 8);
  }

  f4v oacc[2][4] = {};
  float mrow[2] = {-1e30f, -1e30f}, lrow[2] = {0.0f, 0.0f};

  int kv_lo = max(0, t0 - 256);
  int kv_hi = min(T, t0 + 128 + 256);
  int ntiles = (kv_hi - kv_lo) >> 6;

  int srow = tid >> 2, sseg = (tid & 3) * 16;
  const unsigned short* gK = Kb + base + (size_t)(kv_lo + srow) * 1024 + sseg;
  const unsigned short* gV = Vt + vbase + (size_t)srow * 2048 + kv_lo + sseg;
  uint4 rk0 = *(const uint4*)gK, rk1 = *(const uint4*)(gK + 8);
  uint4 rv0 = *(const uint4*)gV, rv1 = *(const uint4*)(gV + 8);

  for (int it = 0; it < ntiles; ++it) {
    int kv0 = kv_lo + (it << 6);
    __syncthreads();  // previous tile's sK/sV reads complete
    *(uint4*)&sK[srow][sseg] = rk0;
    *(uint4*)&sK[srow][sseg + 8] = rk1;
    *(uint4*)&sV[srow][sseg] = rv0;
    *(uint4*)&sV[srow][sseg + 8] = rv1;
    __syncthreads();  // sK/sV ready
    if (it + 1 < ntiles) {  // register prefetch overlaps compute
      const unsigned short* nK = gK + (size_t)(it + 1) * 64 * 1024;
      const unsigned short* nV = gV + (it + 1) * 64;
      rk0 = *(const uint4*)nK; rk1 = *(const uint4*)(nK + 8);
      rv0 = *(const uint4*)nV; rv1 = *(const uint4*)(nV + 8);
    }
    // wave-level skip (barriers at loop top -> barrier-safe); alignment
    // analysis: every row of an active tile has >=1 unmasked key.
    if (kv0 > qlo + 31 + 256 || kv0 + 63 < qlo - 256) continue;

#pragma unroll
    for (int f = 0; f < 2; ++f) {
      int qf = qlo + f * 16;     // wave-uniform
      int qg = qf + l16;         // this lane's q row
      // S^T = K * Q^T : A = K frag (m=key), B = Q frag (n=qrow)
      f4v sacc[4];
#pragma unroll
      for (int nt = 0; nt < 4; ++nt) {
        s8v ak0 = *(const s8v*)&sK[nt * 16 + l16][quad * 8];
        s8v ak1 = *(const s8v*)&sK[nt * 16 + l16][32 + quad * 8];
        f4v zz = {};
        zz = MFMA_BF16(ak0, bq[f][0], zz, 0, 0, 0);
        sacc[nt] = MFMA_BF16(ak1, bq[f][1], sacc[nt] = zz, 0, 0, 0);
      }
      // mask only when the tile isn't fully inside the band (wave-uniform)
      bool full = (kv0 >= qf - 241) && (kv0 <= qf + 193);
      if (!full) {
#pragma unroll
        for (int nt = 0; nt < 4; ++nt) {
          int kg = kv0 + nt * 16 + quad * 4;
#pragma unroll
          for (int r = 0; r < 4; ++r) {
            int d = qg - (kg + r);
            if (d > 256 || d < -256) sacc[nt][r] = -1e30f;
          }
        }
      }
      // row max: in-lane over 16 + cross-quad (2 shfls)
      float mymax = sacc[0][0];
#pragma unroll
      for (int nt = 0; nt < 4; ++nt)
#pragma unroll
        for (int r = 0; r < 4; ++r) mymax = fmaxf(mymax, sacc[nt][r]);
      mymax = fmaxf(mymax, __shfl_xor(mymax, 16));
      mymax = fmaxf(mymax, __shfl_xor(mymax, 32));

      float mn = fmaxf(mrow[f], mymax);
      float alpha = __expf(mrow[f] - mn);
      mrow[f] = mn;

      float mysum = 0.0f;
#pragma unroll
      for (int nt = 0; nt < 4; ++nt) {
        float e0 = __expf(sacc[nt][0] - mn);
        float e1 = __expf(sacc[nt][1] - mn);
        float e2 = __expf(sacc[nt][2] - mn);
        float e3 = __expf(sacc[nt][3] - mn);
        mysum += (e0 + e1) + (e2 + e3);
        *(uint2*)&sP[wave][l16][nt * 16 + quad * 4] =
            make_uint2(pack_bf16(e0, e1), pack_bf16(e2, e3));
      }
      mysum += __shfl_xor(mysum, 16);
      mysum += __shfl_xor(mysum, 32);
      lrow[f] = lrow[f] * alpha + mysum;

      // P^T B-frags (B[k=key][n=qrow]) from this wave's sP region
      s8v pb0 = *(const s8v*)&sP[wave][l16][quad * 8];
      s8v pb1 = *(const s8v*)&sP[wave][l16][32 + quad * 8];

      // O^T += V^T * P^T : A = V^T frag (m=d), B = P^T
#pragma unroll
      for (int dt = 0; dt < 4; ++dt) {
        s8v av0 = *(const s8v*)&sV[dt * 16 + l16][quad * 8];
        s8v av1 = *(const s8v*)&sV[dt * 16 + l16][32 + quad * 8];
        f4v o = oacc[f][dt];
#pragma unroll
        for (int r = 0; r < 4; ++r) o[r] *= alpha;
        o = MFMA_BF16(av0, pb0, o, 0, 0, 0);
        oacc[f][dt] = MFMA_BF16(av1, pb1, o, 0, 0, 0);
      }
    }
  }

  // normalize + store: O^T C-layout -> lane has q-row l16, d = dt*16+quad*4+r
#pragma unroll
  for (int f = 0; f < 2; ++f) {
    float inv = 1.0f / lrow[f];
    size_t rowoff = base + (size_t)(qlo + f * 16 + l16) * 1024;
#pragma unroll
    for (int dt = 0; dt < 4; ++dt) {
      float o0 = oacc[f][dt][0] * inv, o1 = oacc[f][dt][1] * inv;
      float o2 = oacc[f][dt][2] * inv, o3 = oacc[f][dt][3] * inv;
      *(uint2*)&Ab[rowoff + dt * 16 + quad * 4] =
          make_uint2(pack_bf16(o0, o1), pack_bf16(o2, o3));
    }
  }
}

// ---------------- 5) output GEMM (swizzled, m-major): f32 out ---------------
__global__ __launch_bounds__(256) void out_gemm(
    const unsigned short* __restrict__ A, const unsigned short* __restrict__ Bt,
    float* __restrict__ C) {
  const int K = 1024;
  __shared__ __align__(16) unsigned short sA[128 * 64];
  __shared__ __align__(16) unsigned short sB[128 * 64];

  int tid = threadIdx.x;
  int lane = tid & 63, wave = tid >> 6;
  int quad = lane >> 4, l16 = lane & 15;
  int wm = wave & 1, wn = wave >> 1;
  int m_blk = blockIdx.x * 128, n_blk = blockIdx.y * 128;  // m-major!

  f4v acc[4][4] = {};
  int srow = tid >> 3, sg = (tid & 7) ^ (srow & 7);
  const unsigned short* gA = A + (size_t)(m_blk + srow) * K + sg * 8;
  const unsigned short* gB = Bt + (size_t)(n_blk + srow) * K + sg * 8;

  for (int k0 = 0; k0 < K; k0 += 64) {
#pragma unroll
    for (int i = 0; i < 4; ++i) {
      ASYNC_CP16(gA + (size_t)i * 32 * K + k0, &sA[i * 2048 + tid * 8]);
      ASYNC_CP16(gB + (size_t)i * 32 * K + k0, &sB[i * 2048 + tid * 8]);
    }
    __syncthreads();
#pragma unroll
    for (int ks = 0; ks < 64; ks += 32) {
      s8v af[4], bf[4];
#pragma unroll
      for (int mt = 0; mt < 4; ++mt)
        af[mt] = *(const s8v*)&sA[SWZ(wm * 64 + mt * 16 + l16, quad + (ks >> 3))];
#pragma unroll
      for (int nt = 0; nt < 4; ++nt)
        bf[nt] = *(const s8v*)&sB[SWZ(wn * 64 + nt * 16 + l16, quad + (ks >> 3))];
#pragma unroll
      for (int mt = 0; mt < 4; ++mt)
#pragma unroll
        for (int nt = 0; nt < 4; ++nt)
          acc[mt][nt] = MFMA_BF16(af[mt], bf[nt], acc[mt][nt], 0, 0, 0);
    }
    __syncthreads();
  }

#pragma unroll
  for (int mt = 0; mt < 4; ++mt)
#pragma unroll
    for (int nt = 0; nt < 4; ++nt)
#pragma unroll
      for (int r = 0; r < 4; ++r) {
        int row = m_blk + wm * 64 + mt * 16 + quad * 4 + r;
        int col = n_blk + wn * 64 + nt * 16 + l16;
        C[(size_t)row * 1024 + col] = acc[mt][nt][r];
      }
}

// ---------------- launch -----------------------------------------------------
extern "C" void kernel_launch(void* const* d_in, const int* in_sizes, int n_in,
                              void* d_out, int out_size, void* d_ws, size_t ws_size,
                              hipStream_t stream) {
  const float* Xq  = (const float*)d_in[0];
  const float* Xkv = (const float*)d_in[1];
  const float* Wq  = (const float*)d_in[2];
  const float* Wk  = (const float*)d_in[3];
  const float* Wv  = (const float*)d_in[4];
  const float* Wo  = (const float*)d_in[5];
  float* out = (float*)d_out;

  char* ws = (char*)d_ws;
  const size_t MB = 1ull << 20;
  unsigned short* XqBf  = (unsigned short*)(ws + 0 * MB);   // 16 MiB
  unsigned short* XkvBf = (unsigned short*)(ws + 16 * MB);  // 16 MiB
  unsigned short* Wtq   = (unsigned short*)(ws + 32 * MB);  // 2 MiB each
  unsigned short* Wtk   = (unsigned short*)(ws + 34 * MB);
  unsigned short* Wtv   = (unsigned short*)(ws + 36 * MB);
  unsigned short* Wto   = (unsigned short*)(ws + 38 * MB);
  unsigned short* Qb    = (unsigned short*)(ws + 40 * MB);  // 16 MiB
  unsigned short* Kb    = (unsigned short*)(ws + 56 * MB);  // 16 MiB
  unsigned short* Vt    = (unsigned short*)(ws + 72 * MB);  // 16 MiB (transposed V)
  unsigned short* Ab    = XqBf;  // reuse: XqBf dead after proj_gemm

  cvt2_kernel<<<16384, 256, 0, stream>>>(Xq, Xkv, XqBf, XkvBf);
  wtrans_kernel<<<dim3(32, 32, 4), 256, 0, stream>>>(Wq, Wk, Wv, Wo, Wtq, Wtk, Wtv, Wto);
  proj_gemm<<<dim3(64, 8, 3), 256, 0, stream>>>(XqBf, XkvBf, Wtq, Wtk, Wtv, Qb, Kb, Vt);
  attn_kernel<<<dim3(16, 16, 4), 256, 0, stream>>>(Qb, Kb, Vt, Ab);
  out_gemm<<<dim3(64, 8), 256, 0, stream>>>(Ab, Wto, out);
}